// Round 11
// baseline (240.360 us; speedup 1.0000x reference)
//
#include <hip/hip_runtime.h>
#include <hip/hip_bf16.h>

#define DI __device__ __forceinline__

typedef __attribute__((ext_vector_type(8))) short bh8;
typedef __attribute__((ext_vector_type(4))) float f4;

constexpr int  NP        = 65536;              // H*W per batch
constexpr long GP_STRIDE = 20672;              // 5*4096 + 192

// workspace byte offsets
constexpr long WSO_GP    = 0;                                  // [2][128][GP_STRIDE] f32
constexpr long WSO_M     = WSO_GP    + 2L*128*GP_STRIDE*4;     // [2][5][4096] f32
constexpr long WSO_S     = WSO_M     + 2L*5*4096*4;            // [2][192] f32
constexpr long WSO_P     = WSO_S     + 2L*192*4;               // attn [2][2][64][8] f32 (reuse)
constexpr long WSO_QK    = WSO_P     + 2L*5*4096*4;            // unused
constexpr long WSO_G     = WSO_QK    + 2L*2*4096*4;            // [2][2][4096] f32
constexpr long WSO_WKT   = WSO_G     + 2L*2*4096*4;            // unused
constexpr long WSO_WTT   = WSO_WKT   + 4096L*4;                // [9][192][128] f32 (wtapT)
constexpr long WSO_WBA   = WSO_WTT   + 221184L*4;              // [2][36][128][32] bf16 (UNswizzled)
constexpr long WSO_WBB   = WSO_WBA   + 2L*36*4096*2;           // [18][64][32] bf16 (UNswizzled)
constexpr long WSO_XT    = WSO_WBB   + 36864L*2;               // [2][NP][128] bf16 pixel-major [xi;xe]
constexpr long WSO_Y     = WSO_XT    + 2L*NP*128*2;            // [2][NP][128] bf16 pixel-major
constexpr long WSO_STATA = WSO_Y     + 2L*NP*128*2;            // [1024][256] f32
constexpr long WSO_P2A   = WSO_STATA + 1024L*256*4;            // [128][256] f32
constexpr long WSO_BNA   = WSO_P2A   + 128L*256*4;             // [256] f32
constexpr long WSO_Y2    = WSO_BNA   + 256L*4;                 // [2][NP][64] bf16 pixel-major
constexpr long WSO_STATB = WSO_Y2    + 2L*NP*64*2;             // [1024][128] f32
constexpr long WSO_P2B   = WSO_STATB + 1024L*128*4;            // [128][128] f32
constexpr long WSO_BNB   = WSO_P2B   + 128L*128*4;             // [128] f32
constexpr long WS_NEED   = WSO_BNB   + 128L*4;

constexpr int AROWB = 136 * 128;   // bytes per row-strip in conv LDS (136 px * 128 B)
constexpr int ALDSB = 3 * AROWB;   // 52224

DI float b2f(unsigned short u) { return __uint_as_float(((unsigned)u) << 16); }
DI unsigned short f2b(float f) {
  __hip_bfloat16 h = __float2bfloat16(f);
  return *(unsigned short*)&h;
}
DI void gl_lds16(const void* g, void* l) {
  __builtin_amdgcn_global_load_lds(
      (const __attribute__((address_space(1))) unsigned int*)g,
      (__attribute__((address_space(3))) unsigned int*)l, 16, 0, 0);
}

// NOTE: parameter names must not collide with .x/.y/.z/.w member tokens
#define FMA4(acc, S_, V_)                                                      \
  acc.x = fmaf(S_, V_.x, acc.x); acc.y = fmaf(S_, V_.y, acc.y);                \
  acc.z = fmaf(S_, V_.z, acc.z); acc.w = fmaf(S_, V_.w, acc.w);

// ---------------- K0: static weight re-layouts (wtapT + conv B) ----------------
__global__ __launch_bounds__(256) void k0_prep(const float* __restrict__ w_init,
                                               const float* __restrict__ w1,
                                               const float* __restrict__ w2,
                                               float* __restrict__ wtapT,
                                               unsigned short* __restrict__ wBB) {
  int i = blockIdx.x * 256 + threadIdx.x;
  if (i < 221184) {                 // wtapT[tap][cin][oc]
    int tap = i / 24576;
    int rem = i % 24576;
    int cin = rem >> 7, oc = rem & 127;
    float v = (oc < 64) ? w_init[(oc * 192 + cin) * 9 + tap]
                        : w1[((oc - 64) * 192 + cin) * 9 + tap];
    wtapT[i] = v;
  } else if (i < 258048) {          // conv B weights: step = tap*2 + s  (UNswizzled)
    int j = i - 221184;
    int step = j >> 11;
    int rem = j & 2047;
    int oc = rem >> 5, kk = rem & 31;
    int tap = step >> 1, s = step & 1;
    int c = s * 32 + kk;
    wBB[(step << 11) + (oc << 5) + kk] = f2b(w2[(oc * 64 + c) * 9 + tap]);
  }
}

// ---------------- K1: per-b Gram matrices via MFMA (hi/lo bf16 split) ----------------
__global__ __launch_bounds__(512, 2) void k1_gram(const float* __restrict__ xi,
                                                  const float* __restrict__ xe,
                                                  const float* __restrict__ yy,
                                                  float* __restrict__ gp) {
  __shared__ alignas(16) char lds[2 * 49152];   // dbuf x [3t][2p][64c][128B] swizzled
  int tid = threadIdx.x;
  int lane = tid & 63, wave = tid >> 6;
  int i_t = wave & 3, jh = wave >> 2;
  int blk = blockIdx.x, b = blockIdx.y;
  const float* srcs[3];
  srcs[0] = yy + (long)b * 64 * NP;
  srcs[1] = xe + (long)b * 64 * NP;
  srcs[2] = xi + (long)b * 64 * NP;

  f4 zero = {0.f, 0.f, 0.f, 0.f};
  f4 acc[5][2];
#pragma unroll
  for (int g = 0; g < 5; ++g) { acc[g][0] = zero; acc[g][1] = zero; }
  float rs[6] = {0.f, 0.f, 0.f, 0.f, 0.f, 0.f};

  int rowv[6], col4v[6], tv[6], cv[6];
#pragma unroll
  for (int ii = 0; ii < 6; ++ii) {
    int li = ii * 512 + tid;
    rowv[ii] = li >> 4; col4v[ii] = li & 15;
    tv[ii] = rowv[ii] >> 6; cv[ii] = rowv[ii] & 63;
  }

  float4 v[6];
#define LOADS(S)                                                                \
  { int n0 = blk * 512 + (S) * 64;                                              \
    _Pragma("unroll") for (int ii = 0; ii < 6; ++ii)                            \
      v[ii] = *(const float4*)(srcs[tv[ii]] + (long)cv[ii] * NP + n0 + col4v[ii] * 4); }
#define CVTW(BUF)                                                               \
  { _Pragma("unroll") for (int ii = 0; ii < 6; ++ii) {                          \
      rs[ii] += v[ii].x + v[ii].y + v[ii].z + v[ii].w;                          \
      ushort4 hi, lo;                                                           \
      hi.x = f2b(v[ii].x); lo.x = f2b(v[ii].x - b2f(hi.x));                     \
      hi.y = f2b(v[ii].y); lo.y = f2b(v[ii].y - b2f(hi.y));                     \
      hi.z = f2b(v[ii].z); lo.z = f2b(v[ii].z - b2f(hi.z));                     \
      hi.w = f2b(v[ii].w); lo.w = f2b(v[ii].w - b2f(hi.w));                     \
      int base = (BUF) * 49152 + (tv[ii] * 2 * 64 + cv[ii]) * 128;              \
      int colo = (col4v[ii] * 8) ^ ((cv[ii] & 7) << 4);                         \
      *(ushort4*)(lds + base + colo) = hi;                                      \
      *(ushort4*)(lds + base + 8192 + colo) = lo; } }

  LOADS(0)
  CVTW(0)
  for (int s = 0; s < 8; ++s) {
    int buf = s & 1;
    __syncthreads();
    if (s < 7) LOADS(s + 1)     // issued post-barrier: hide under ds_read+MFMA
    const char* lb = lds + buf * 49152;
#pragma unroll
    for (int kk = 0; kk < 2; ++kk) {
      bh8 ah[3], al[3];
#pragma unroll
      for (int t = 0; t < 3; ++t) {
        int cc = i_t * 16 + (lane & 15);
        int col = (kk * 64 + ((lane >> 4) << 4)) ^ ((cc & 7) << 4);
        ah[t] = *(const bh8*)(lb + ((t * 2) * 64 + cc) * 128 + col);
        al[t] = *(const bh8*)(lb + ((t * 2) * 64 + cc) * 128 + 8192 + col);
      }
#pragma unroll
      for (int jj = 0; jj < 2; ++jj) {
        int j = jh * 2 + jj;
        bh8 bh_[3], bl_[3];
#pragma unroll
        for (int t = 0; t < 3; ++t) {
          int dd = j * 16 + (lane & 15);
          int col = (kk * 64 + ((lane >> 4) << 4)) ^ ((dd & 7) << 4);
          bh_[t] = *(const bh8*)(lb + ((t * 2) * 64 + dd) * 128 + col);
          bl_[t] = *(const bh8*)(lb + ((t * 2) * 64 + dd) * 128 + 8192 + col);
        }
#define GRAM(G, TA, TB)                                                            \
        acc[G][jj] = __builtin_amdgcn_mfma_f32_16x16x32_bf16(ah[TA], bh_[TB], acc[G][jj], 0, 0, 0); \
        acc[G][jj] = __builtin_amdgcn_mfma_f32_16x16x32_bf16(ah[TA], bl_[TB], acc[G][jj], 0, 0, 0); \
        acc[G][jj] = __builtin_amdgcn_mfma_f32_16x16x32_bf16(al[TA], bh_[TB], acc[G][jj], 0, 0, 0);
        GRAM(0, 0, 1) GRAM(1, 0, 2) GRAM(2, 0, 0) GRAM(3, 1, 1) GRAM(4, 2, 2)
#undef GRAM
      }
    }
    if (s < 7) CVTW(buf ^ 1)
  }
#undef LOADS
#undef CVTW

  float* outp = gp + ((long)b * 128 + blk) * GP_STRIDE;
#pragma unroll
  for (int g = 0; g < 5; ++g)
#pragma unroll
    for (int jj = 0; jj < 2; ++jj) {
      int j = jh * 2 + jj;
#pragma unroll
      for (int r = 0; r < 4; ++r) {
        int cg = i_t * 16 + ((lane >> 4) << 2) + r;
        int dg = j * 16 + (lane & 15);
        outp[g * 4096 + cg * 64 + dg] = acc[g][jj][r];
      }
    }
#pragma unroll
  for (int ii = 0; ii < 6; ++ii) {
    float s = rs[ii];
    s += __shfl_xor(s, 1); s += __shfl_xor(s, 2);
    s += __shfl_xor(s, 4); s += __shfl_xor(s, 8);
    if ((lane & 15) == 0) outp[5 * 4096 + rowv[ii]] = s;
  }
}

// ---------------- K1r: reduce Gram partials ----------------
__global__ __launch_bounds__(256) void k1_reduce(const float* __restrict__ gp,
                                                 float* __restrict__ M,
                                                 float* __restrict__ S) {
  int i = blockIdx.x * 256 + threadIdx.x;
  if (i >= 2 * GP_STRIDE) return;
  int b = i / GP_STRIDE, o = i % GP_STRIDE;
  const float* p = gp + (long)b * 128 * GP_STRIDE + o;
  float s = 0;
  for (int k = 0; k < 128; ++k) s += p[(long)k * GP_STRIDE];
  if (o < 20480) M[b * 20480 + o] = s;
  else           S[b * 192 + (o - 20480)] = s;
}

// ---------------- K2a: row-split attention front-end (grid 4x2) ----------------
__global__ __launch_bounds__(256) void k2_attn(const float* __restrict__ M,
                                               const float* __restrict__ Ssum,
                                               const float* __restrict__ wq,
                                               const float* __restrict__ wk,
                                               const float* __restrict__ bq,
                                               const float* __restrict__ bk,
                                               const float* __restrict__ temp,
                                               float* __restrict__ attnG) {
  __shared__ float Ms[5 * 4096];       // all five M matrices (80 KB)
  __shared__ float WQr[16 * 68];
  __shared__ float WKr[16 * 68];
  __shared__ float Ps[16 * 68];
  __shared__ float QKs[16 * 17];
  __shared__ float Ss[192], bqs[16], bks[16], tt[2];
  __shared__ float uu[16], ve[16], vi[16];
  __shared__ float dqv[16], dkev[16], dkiv[16];
  __shared__ float nqs[16], nkes[16], nkis[16];

  int r = blockIdx.x, b = blockIdx.y, tid = threadIdx.x;
  int i0 = r * 16;
  const float* Mb = M + b * 20480;
#pragma unroll
  for (int it = 0; it < 20; ++it) {
    int slot = it * 256 + tid;
    *(float4*)&Ms[slot * 4] = *(const float4*)(Mb + slot * 4);
  }
  {
    int row = tid >> 4, c4 = (tid & 15) * 4;
    *(float4*)&WQr[row * 68 + c4] = *(const float4*)(wq + (i0 + row) * 64 + c4);
    *(float4*)&WKr[row * 68 + c4] = *(const float4*)(wk + (i0 + row) * 64 + c4);
  }
  if (tid < 192) Ss[tid] = Ssum[b * 192 + tid];
  else if (tid < 208) bqs[tid - 192] = bq[i0 + tid - 192];
  else if (tid < 224) bks[tid - 208] = bk[i0 + tid - 208];
  else if (tid < 226) tt[tid - 224] = temp[2 * r + (tid - 224)];
  __syncthreads();

  int il = tid >> 4, q = tid & 15, j0 = q * 4;
  {
    float4 a = *(const float4*)&WQr[il * 68 + j0];
    float4 c = *(const float4*)&WKr[il * 68 + j0];
    float pu = a.x * Ss[j0] + a.y * Ss[j0 + 1] + a.z * Ss[j0 + 2] + a.w * Ss[j0 + 3];
    float pe = c.x * Ss[64 + j0] + c.y * Ss[64 + j0 + 1] + c.z * Ss[64 + j0 + 2] + c.w * Ss[64 + j0 + 3];
    float pi = c.x * Ss[128 + j0] + c.y * Ss[128 + j0 + 1] + c.z * Ss[128 + j0 + 2] + c.w * Ss[128 + j0 + 3];
#pragma unroll
    for (int m = 1; m <= 8; m <<= 1) {
      pu += __shfl_xor(pu, m); pe += __shfl_xor(pe, m); pi += __shfl_xor(pi, m);
    }
    if (q == 0) { uu[il] = pu; ve[il] = pe; vi[il] = pi; }
  }
  // diagonal quadratic forms d = w_i^T M_g w_i for g = 2,3,4
#pragma unroll
  for (int t = 0; t < 3; ++t) {
    const float* W = (t == 0) ? WQr : WKr;
    const float* Mg = &Ms[(2 + t) * 4096];
    float4 t4 = {0.f, 0.f, 0.f, 0.f};
    for (int k4 = 0; k4 < 64; k4 += 4) {
      float4 w4 = *(const float4*)&W[il * 68 + k4];
      float4 m0 = *(const float4*)&Mg[(k4 + 0) * 64 + j0];
      float4 m1 = *(const float4*)&Mg[(k4 + 1) * 64 + j0];
      float4 m2 = *(const float4*)&Mg[(k4 + 2) * 64 + j0];
      float4 m3 = *(const float4*)&Mg[(k4 + 3) * 64 + j0];
      FMA4(t4, w4.x, m0) FMA4(t4, w4.y, m1) FMA4(t4, w4.z, m2) FMA4(t4, w4.w, m3)
    }
    float4 wj = *(const float4*)&W[il * 68 + j0];
    float d = t4.x * wj.x + t4.y * wj.y + t4.z * wj.z + t4.w * wj.w;
#pragma unroll
    for (int m = 1; m <= 8; m <<= 1) d += __shfl_xor(d, m);
    if (q == 0) {
      if (t == 0) dqv[il] = d; else if (t == 1) dkev[il] = d; else dkiv[il] = d;
    }
  }
  __syncthreads();
  if (tid < 16) {
    const float N = 65536.f;
    float bqi = bqs[tid], bki = bks[tid];
    nqs[tid]  = fmaxf(sqrtf(fmaxf(dqv[tid]  + 2.f * uu[tid] * bqi + N * bqi * bqi, 0.f)), 1e-12f);
    nkes[tid] = fmaxf(sqrtf(fmaxf(dkev[tid] + 2.f * ve[tid] * bki + N * bki * bki, 0.f)), 1e-12f);
    nkis[tid] = fmaxf(sqrtf(fmaxf(dkiv[tid] + 2.f * vi[tid] * bki + N * bki * bki, 0.f)), 1e-12f);
  }
  __syncthreads();

  for (int v = 0; v < 2; ++v) {
    const float* Mg = &Ms[v * 4096];
    float4 p4 = {0.f, 0.f, 0.f, 0.f};
    for (int k4 = 0; k4 < 64; k4 += 4) {
      float4 w4 = *(const float4*)&WQr[il * 68 + k4];
      float4 m0 = *(const float4*)&Mg[(k4 + 0) * 64 + j0];
      float4 m1 = *(const float4*)&Mg[(k4 + 1) * 64 + j0];
      float4 m2 = *(const float4*)&Mg[(k4 + 2) * 64 + j0];
      float4 m3 = *(const float4*)&Mg[(k4 + 3) * 64 + j0];
      FMA4(p4, w4.x, m0) FMA4(p4, w4.y, m1) FMA4(p4, w4.z, m2) FMA4(p4, w4.w, m3)
    }
    *(float4*)&Ps[il * 68 + j0] = p4;
    __syncthreads();
    {
      int i2 = tid >> 4, jl = tid & 15;
      float s = 0.f;
      for (int k4 = 0; k4 < 64; k4 += 4) {
        float4 pp = *(const float4*)&Ps[i2 * 68 + k4];
        float4 kk = *(const float4*)&WKr[jl * 68 + k4];
        s += pp.x * kk.x + pp.y * kk.y + pp.z * kk.z + pp.w * kk.w;
      }
      QKs[i2 * 17 + jl] = s;
    }
    __syncthreads();
    if (tid < 128) {
      int i2 = tid >> 3, d = tid & 7;
      int h2 = i2 >> 3;
      int jl = h2 * 8 + d;
      float vx = v ? vi[jl] : ve[jl];
      float nk = v ? nkis[jl] : nkes[jl];
      float bqi = bqs[i2], bkj = bks[jl];
      float val = QKs[i2 * 17 + jl] + uu[i2] * bkj + bqi * vx + 65536.f * bqi * bkj;
      val = val / (nqs[i2] * nk) * tt[h2];
      float mx = val;
      mx = fmaxf(mx, __shfl_xor(mx, 1));
      mx = fmaxf(mx, __shfl_xor(mx, 2));
      mx = fmaxf(mx, __shfl_xor(mx, 4));
      float ex = expf(val - mx);
      float se = ex;
      se += __shfl_xor(se, 1); se += __shfl_xor(se, 2); se += __shfl_xor(se, 4);
      attnG[((long)(b * 2 + v) * 64 + i0 + i2) * 8 + d] = ex / se;
    }
    __syncthreads();
  }
}

// ---------------- K2b: row-split G = wo . BD(attn) . wv (grid 4x2) ----------------
__global__ __launch_bounds__(256) void k2_g(const float* __restrict__ attnG,
                                            const float* __restrict__ wo,
                                            const float* __restrict__ wv,
                                            float* __restrict__ G) {
  __shared__ float WVs[4096];
  __shared__ float WOr[16 * 68];
  __shared__ float As[2 * 64 * 12];
  __shared__ float Gm[16 * 68];
  int ro = blockIdx.x, b = blockIdx.y, tid = threadIdx.x;
  int o0 = ro * 16;
#pragma unroll
  for (int it = 0; it < 4; ++it) {
    int slot = it * 256 + tid;
    *(float4*)&WVs[slot * 4] = *(const float4*)(wv + slot * 4);
  }
  {
    int row = tid >> 4, c4 = (tid & 15) * 4;
    *(float4*)&WOr[row * 68 + c4] = *(const float4*)(wo + (o0 + row) * 64 + c4);
  }
#pragma unroll
  for (int it = 0; it < 4; ++it) {
    int slot = it * 256 + tid;     // 1024 = 2v * 64row * 8d
    int v = slot >> 9, rr = (slot >> 3) & 63, d = slot & 7;
    As[v * 768 + rr * 12 + d] = attnG[((long)(b * 2 + v) * 64 + rr) * 8 + d];
  }
  __syncthreads();
  int ol = tid >> 4, q = tid & 15, j0 = q * 4;
  int h = q >> 1, dbase = (q & 1) * 4;
  for (int v = 0; v < 2; ++v) {
    float4 g4 = {0.f, 0.f, 0.f, 0.f};
#pragma unroll
    for (int c = 0; c < 8; ++c) {
      float w = WOr[ol * 68 + h * 8 + c];
      float4 a4 = *(const float4*)&As[v * 768 + (h * 8 + c) * 12 + dbase];
      FMA4(g4, w, a4)
    }
    *(float4*)&Gm[ol * 68 + j0] = g4;
    __syncthreads();
    float4 a4 = {0.f, 0.f, 0.f, 0.f};
    for (int m4 = 0; m4 < 64; m4 += 4) {
      float4 gm4 = *(const float4*)&Gm[ol * 68 + m4];
      float4 r0 = *(const float4*)&WVs[(m4 + 0) * 64 + j0];
      float4 r1 = *(const float4*)&WVs[(m4 + 1) * 64 + j0];
      float4 r2 = *(const float4*)&WVs[(m4 + 2) * 64 + j0];
      float4 r3 = *(const float4*)&WVs[(m4 + 3) * 64 + j0];
      FMA4(a4, gm4.x, r0) FMA4(a4, gm4.y, r1) FMA4(a4, gm4.z, r2) FMA4(a4, gm4.w, r3)
    }
    *(float4*)(G + ((long)(b * 2 + v)) * 4096 + (o0 + ol) * 64 + j0) = a4;
    __syncthreads();
  }
}

// ---------------- K3t: transpose x_i,x_e -> [b][px][128ch] bf16 pixel-major ----------------
__global__ __launch_bounds__(256) void k3_xt(const float* __restrict__ xi,
                                             const float* __restrict__ xe,
                                             unsigned short* __restrict__ xt) {
  __shared__ float st[2][64][66];
  int tid = threadIdx.x;
  int b = blockIdx.y;
  int px0 = blockIdx.x * 64;
  for (int it = 0; it < 8; ++it) {
    int slot = it * 256 + tid;          // 2048 = 2t * 64c * 16 float4
    int t = slot >> 10, r = slot & 1023, c = r >> 4, j = r & 15;
    const float* s = (t ? xe : xi) + ((long)b * 64 + c) * NP + px0 + j * 4;
    float4 v = *(const float4*)s;
    st[t][j * 4 + 0][c] = v.x;
    st[t][j * 4 + 1][c] = v.y;
    st[t][j * 4 + 2][c] = v.z;
    st[t][j * 4 + 3][c] = v.w;
  }
  __syncthreads();
  unsigned short* xb = xt + ((long)b * NP + px0) * 128;
  for (int it = 0; it < 4; ++it) {
    int slot = it * 256 + tid;          // 1024 = 64px * 16 chunks(8ch)
    int px = slot >> 4, c8 = slot & 15;
    int t = c8 >> 3, cb = (c8 & 7) * 8;
    bh8 o;
#pragma unroll
    for (int e = 0; e < 8; ++e) o[e] = (short)f2b(st[t][px][cb + e]);
    *(bh8*)(xb + (long)px * 128 + c8 * 8) = o;
  }
}

// ---------------- K3w: composed conv-A weights W'_b = Wcat . Gstack_b (bf16, UNswizzled) ----------------
__global__ __launch_bounds__(256) void k3_wprep(const float* __restrict__ wtapT,
                                                const float* __restrict__ G,
                                                unsigned short* __restrict__ wBA) {
  __shared__ float Gs[2][64][8];    // [variant e/i][row j][cn-local]
  int tid = threadIdx.x;
  int tap = blockIdx.x, b = blockIdx.y, g = blockIdx.z;
  const float* Gb = G + (long)b * 2 * 4096;
  for (int it = 0; it < 4; ++it) {
    int slot = it * 256 + tid;        // 1024 = 2v * 64j * 8e
    int v = slot >> 9, r = slot & 511, j = r >> 3, e = r & 7;
    Gs[v][j][e] = Gb[v * 4096 + j * 64 + g * 8 + e];
  }
  __syncthreads();
  int h = tid >> 7, oc = tid & 127;
  const float* wt = wtapT + (long)tap * 24576;
  float acc[8] = {0.f, 0.f, 0.f, 0.f, 0.f, 0.f, 0.f, 0.f};
  if (h == 0) {
    for (int j = 0; j < 64; ++j) {
      float w0 = wt[j * 128 + oc];
      float w2v = wt[(128 + j) * 128 + oc];
      const float* ge = &Gs[0][j][0];
      const float* gi = &Gs[1][j][0];
#pragma unroll
      for (int e = 0; e < 8; ++e) acc[e] += w0 * ge[e] + w2v * gi[e];
    }
  } else {
    for (int j = 0; j < 64; ++j) {
      float w0 = wt[(64 + j) * 128 + oc];
      const float* ge = &Gs[0][j][0];
#pragma unroll
      for (int e = 0; e < 8; ++e) acc[e] += w0 * ge[e];
    }
  }
  unsigned short* wb = wBA + (long)b * 36 * 4096;
  int s = g >> 2;
  int step = h * 18 + tap * 2 + s;
#pragma unroll
  for (int e = 0; e < 8; ++e) {
    int kk = (g & 3) * 8 + e;
    wb[step * 4096 + oc * 32 + kk] = f2b(acc[e]);
  }
}

// ---------------- K4: conv3x3 reflect 128->128 via MFMA, B in registers, 3 blocks/CU ----------------
__global__ __launch_bounds__(256, 3) void k4_mfma(const unsigned short* __restrict__ xt,
                                                  const unsigned short* __restrict__ wBA,
                                                  unsigned short* __restrict__ yout,
                                                  float* __restrict__ statp) {
  __shared__ alignas(16) char lds[ALDSB + 1024];
  float* statf = (float*)(lds + ALDSB);

  int tid = threadIdx.x;
  int wave = tid >> 6, lane = tid & 63;
  int kc = lane >> 4, i16 = lane & 15;

  int bid = blockIdx.x;
  int blk = (bid & 7) * 128 + (bid >> 3);   // bijective XCD swizzle (1024 % 8 == 0)
  int b = blk >> 9, y = (blk >> 1) & 255, xtile = blk & 1;
  int x0 = xtile << 7;
  int rows[3] = {y > 0 ? y - 1 : 1, y, y < 255 ? y + 1 : 254};

  const unsigned short* fb = xt + (long)b * NP * 128;
  const char* wBAb = (const char*)(wBA + (long)b * 36 * 4096);
  statf[tid] = 0.f;

  int wm = wave & 1, wn = wave >> 1;
  int m0 = wm * 64, n0 = wn * 64;
  int boff = (n0 + i16) * 64 + kc * 16;     // per-lane B byte offset within a step

  f4 zero = {0.f, 0.f, 0.f, 0.f};
  f4 acc[4][4];
#pragma unroll
  for (int i = 0; i < 4; ++i)
#pragma unroll
    for (int j = 0; j < 4; ++j) acc[i][j] = zero;

#define LOADB4(ST, BF)                                                         \
  { const char* wsrc_ = wBAb + (long)(ST) * 8192 + boff;                       \
    BF[0] = *(const bh8*)(wsrc_);                                              \
    BF[1] = *(const bh8*)(wsrc_ + 1024);                                       \
    BF[2] = *(const bh8*)(wsrc_ + 2048);                                       \
    BF[3] = *(const bh8*)(wsrc_ + 3072); }

#define STEP4(STL, BF)                                                         \
  { int tap_ = (STL) >> 1, s_ = (STL) & 1;                                     \
    int kx_ = tap_ % 3, rowk_ = tap_ / 3;                                      \
    const char* arow_ = lds + rowk_ * AROWB;                                   \
    int cbb_ = s_ * 64 + kc * 16;                                              \
    bh8 af_[4];                                                                \
    _Pragma("unroll") for (int mf = 0; mf < 4; ++mf) {                         \
      int pxl_ = kx_ + m0 + mf * 16 + i16;                                     \
      af_[mf] = *(const bh8*)(arow_ + pxl_ * 128 + (cbb_ ^ ((pxl_ & 7) << 4)));\
    }                                                                          \
    _Pragma("unroll") for (int mf = 0; mf < 4; ++mf)                           \
      _Pragma("unroll") for (int nf = 0; nf < 4; ++nf)                         \
        acc[mf][nf] = __builtin_amdgcn_mfma_f32_16x16x32_bf16(af_[mf], BF[nf], acc[mf][nf], 0, 0, 0); }

  bh8 B0[4], B1[4], B2[4];
  LOADB4(0, B0)
  LOADB4(1, B1)
  LOADB4(2, B2)

  for (int ch = 0; ch < 2; ++ch) {
    __syncthreads();                        // prior chunk readers done
#pragma unroll
    for (int it = 0; it < 13; ++it) {
      int base = (wave * 13 + it) << 10;
      if (base < ALDSB) {
        int slot = base + lane * 16;
        int row = slot / AROWB;
        int rr = slot - row * AROWB;
        int px = rr >> 7, cb = rr & 127;
        int pxl = px < 130 ? px : 129;
        int gx = x0 - 1 + pxl;
        gx = gx < 0 ? 1 : (gx > 255 ? 254 : gx);
        int cbs = cb ^ ((px & 7) << 4);
        const char* src = (const char*)(fb + (long)(rows[row] * 256 + gx) * 128 + ch * 64) + cbs;
        gl_lds16(src, lds + base);
      }
    }
    __syncthreads();                        // A staged

#pragma unroll
    for (int g3 = 0; g3 < 6; ++g3) {
      int stl = g3 * 3;
      int st = ch * 18 + stl;
      STEP4(stl, B0)
      if (st + 3 < 36) LOADB4(st + 3, B0)
      STEP4(stl + 1, B1)
      if (st + 4 < 36) LOADB4(st + 4, B1)
      STEP4(stl + 2, B2)
      if (st + 5 < 36) LOADB4(st + 5, B2)
    }
  }
#undef LOADB4
#undef STEP4

#pragma unroll
  for (int nf = 0; nf < 4; ++nf) {
    float s1 = 0.f, s2 = 0.f;
#pragma unroll
    for (int mf = 0; mf < 4; ++mf)
#pragma unroll
      for (int r = 0; r < 4; ++r) {
        float v = acc[mf][nf][r];
        s1 += v; s2 += v * v;
      }
    s1 += __shfl_xor(s1, 16); s2 += __shfl_xor(s2, 16);
    s1 += __shfl_xor(s1, 32); s2 += __shfl_xor(s2, 32);
    if (lane < 16) {
      int oc = n0 + nf * 16 + i16;
      atomicAdd(&statf[oc * 2], s1);
      atomicAdd(&statf[oc * 2 + 1], s2);
    }
  }
  __syncthreads();
#pragma unroll
  for (int nf = 0; nf < 4; ++nf) {
    int oc2 = (n0 + nf * 16 + i16) * 2;
#pragma unroll
    for (int mf = 0; mf < 4; ++mf)
#pragma unroll
      for (int r = 0; r < 4; ++r) {
        int px = m0 + mf * 16 + kc * 4 + r;
        *(unsigned short*)(lds + px * 256 + (oc2 ^ ((px & 7) << 4))) = f2b(acc[mf][nf][r]);
      }
  }
  __syncthreads();
  unsigned short* yb = yout + (long)b * NP * 128;
#pragma unroll
  for (int it = 0; it < 8; ++it) {
    int slot = (it * 256 + tid) * 16;
    int px = slot >> 8, cb = slot & 255;
    int cbs = cb ^ ((px & 7) << 4);
    f4 v = *(const f4*)(lds + px * 256 + cbs);
    *(f4*)((char*)(yb + (long)(y * 256 + x0 + px) * 128) + cb) = v;
  }
  statp[(long)bid * 256 + tid] = statf[tid];
}

// ---------------- K5a/K5b: BN stat reduce (conv A) ----------------
__global__ __launch_bounds__(256) void k5a(const float* __restrict__ statp, float* __restrict__ p2) {
  int rblk = blockIdx.x, tid = threadIdx.x;
  float s = 0;
  for (int k = 0; k < 8; ++k) s += statp[(long)(rblk * 8 + k) * 256 + tid];
  p2[rblk * 256 + tid] = s;
}

__global__ __launch_bounds__(256) void k5b(const float* __restrict__ p2,
                                           const float* __restrict__ g_init,
                                           const float* __restrict__ be_init,
                                           const float* __restrict__ g1,
                                           const float* __restrict__ be1,
                                           float* __restrict__ bnA) {
  int tid = threadIdx.x;
  float s = 0;
  for (int k = 0; k < 128; ++k) s += p2[k * 256 + tid];
  __shared__ float sm[256];
  sm[tid] = s;
  __syncthreads();
  if (tid < 128) {
    int oc = tid;
    float mean = sm[oc * 2] * (1.f / 131072.f);
    float var = sm[oc * 2 + 1] * (1.f / 131072.f) - mean * mean;
    float g  = oc < 64 ? g_init[oc] : g1[oc - 64];
    float be = oc < 64 ? be_init[oc] : be1[oc - 64];
    float sc = g * rsqrtf(fmaxf(var, 0.f) + 1e-5f);
    bnA[oc * 2] = sc;
    bnA[oc * 2 + 1] = be - mean * sc;
  }
}

// ---------------- K6: conv3x3 reflect relu(bn1(y1)) -> 64 via MFMA, B in regs, 3 blocks/CU ----------------
__global__ __launch_bounds__(256, 3) void k6_mfma(const unsigned short* __restrict__ yws,
                                                  const unsigned short* __restrict__ wBB,
                                                  const float* __restrict__ bnA,
                                                  unsigned short* __restrict__ y2,
                                                  float* __restrict__ statp) {
  __shared__ alignas(16) char lds[ALDSB + 512];
  float* statf = (float*)(lds + ALDSB);

  int tid = threadIdx.x;
  int wave = tid >> 6, lane = tid & 63;
  int kc = lane >> 4, i16 = lane & 15;

  int bid = blockIdx.x;
  int blk = (bid & 7) * 128 + (bid >> 3);
  int b = blk >> 9, y = (blk >> 1) & 255, xtile = blk & 1;
  int x0 = xtile << 7;
  int rows[3] = {y > 0 ? y - 1 : 1, y, y < 255 ? y + 1 : 254};

  if (tid < 128) statf[tid] = 0.f;

  int wm = wave & 1, wn = wave >> 1;
  int m0 = wm * 64, n0 = wn * 32;
  int boff = (n0 + i16) * 64 + kc * 16;

#define LOADB2(ST, BF)                                                         \
  { const char* wsrc_ = (const char*)wBB + (long)(ST) * 4096 + boff;           \
    BF[0] = *(const bh8*)(wsrc_);                                              \
    BF[1] = *(const bh8*)(wsrc_ + 1024); }

  bh8 B0[2], B1[2], B2[2];
  LOADB2(0, B0)
  LOADB2(1, B1)
  LOADB2(2, B2)

  int c0 = (tid & 7) * 8;
  float sc[8], bi[8];
#pragma unroll
  for (int e = 0; e < 8; ++e) {
    int cc = 64 + c0 + e;
    sc[e] = bnA[cc * 2];
    bi[e] = bnA[cc * 2 + 1];
  }
  const unsigned short* yb = yws + (long)b * NP * 128;
  int pbase = tid >> 3;
  for (int r = 0; r < 13; ++r) {
    int p = pbase + r * 32;
    if (p < 408) {
      int row = p / 136, pxs = p - row * 136;
      int pxl = pxs < 130 ? pxs : 129;
      int gx = x0 - 1 + pxl;
      gx = gx < 0 ? 1 : (gx > 255 ? 254 : gx);
      const unsigned short* src = yb + (long)(rows[row] * 256 + gx) * 128 + 64 + c0;
      bh8 v = *(const bh8*)src;
      bh8 o;
#pragma unroll
      for (int e = 0; e < 8; ++e) {
        float f = fmaxf(b2f((unsigned short)v[e]) * sc[e] + bi[e], 0.f);
        o[e] = (short)f2b(f);
      }
      *(bh8*)(lds + p * 128 + ((c0 * 2) ^ ((pxs & 7) << 4))) = o;
    }
  }
  __syncthreads();

  f4 zero = {0.f, 0.f, 0.f, 0.f};
  f4 acc[4][2];
#pragma unroll
  for (int i = 0; i < 4; ++i) { acc[i][0] = zero; acc[i][1] = zero; }

#define STEP6(STL, BF)                                                         \
  { int tap_ = (STL) >> 1, s_ = (STL) & 1;                                     \
    int kx_ = tap_ % 3, rowk_ = tap_ / 3;                                      \
    const char* arow_ = lds + rowk_ * AROWB;                                   \
    int cbb_ = s_ * 64 + kc * 16;                                              \
    bh8 af_[4];                                                                \
    _Pragma("unroll") for (int mf = 0; mf < 4; ++mf) {                         \
      int pxl_ = kx_ + m0 + mf * 16 + i16;                                     \
      af_[mf] = *(const bh8*)(arow_ + pxl_ * 128 + (cbb_ ^ ((pxl_ & 7) << 4)));\
    }                                                                          \
    _Pragma("unroll") for (int mf = 0; mf < 4; ++mf)                           \
      _Pragma("unroll") for (int nf = 0; nf < 2; ++nf)                         \
        acc[mf][nf] = __builtin_amdgcn_mfma_f32_16x16x32_bf16(af_[mf], BF[nf], acc[mf][nf], 0, 0, 0); }

#pragma unroll
  for (int g3 = 0; g3 < 6; ++g3) {
    int st = g3 * 3;
    STEP6(st, B0)
    if (st + 3 < 18) LOADB2(st + 3, B0)
    STEP6(st + 1, B1)
    if (st + 4 < 18) LOADB2(st + 4, B1)
    STEP6(st + 2, B2)
    if (st + 5 < 18) LOADB2(st + 5, B2)
  }
#undef LOADB2
#undef STEP6

#pragma unroll
  for (int nf = 0; nf < 2; ++nf) {
    float s1 = 0.f, s2 = 0.f;
#pragma unroll
    for (int mf = 0; mf < 4; ++mf)
#pragma unroll
      for (int r = 0; r < 4; ++r) {
        float v = acc[mf][nf][r];
        s1 += v; s2 += v * v;
      }
    s1 += __shfl_xor(s1, 16); s2 += __shfl_xor(s2, 16);
    s1 += __shfl_xor(s1, 32); s2 += __shfl_xor(s2, 32);
    if (lane < 16) {
      int oc = n0 + nf * 16 + i16;
      atomicAdd(&statf[oc * 2], s1);
      atomicAdd(&statf[oc * 2 + 1], s2);
    }
  }
  __syncthreads();
#pragma unroll
  for (int nf = 0; nf < 2; ++nf) {
    int oc2 = (n0 + nf * 16 + i16) * 2;
#pragma unroll
    for (int mf = 0; mf < 4; ++mf)
#pragma unroll
      for (int r = 0; r < 4; ++r) {
        int px = m0 + mf * 16 + kc * 4 + r;
        *(unsigned short*)(lds + px * 128 + (oc2 ^ ((px & 7) << 4))) = f2b(acc[mf][nf][r]);
      }
  }
  __syncthreads();
  unsigned short* y2b = y2 + (long)b * NP * 64;
#pragma unroll
  for (int it = 0; it < 4; ++it) {
    int slot = (it * 256 + tid) * 16;
    int px = slot >> 7, cb = slot & 127;
    int cbs = cb ^ ((px & 7) << 4);
    f4 v = *(const f4*)(lds + px * 128 + cbs);
    *(f4*)((char*)(y2b + (long)(y * 256 + x0 + px) * 64) + cb) = v;
  }
  if (tid < 128) statp[(long)bid * 128 + tid] = statf[tid];
}

// ---------------- K7a/K7b: BN stat reduce (conv B) ----------------
__global__ __launch_bounds__(128) void k7a(const float* __restrict__ statp, float* __restrict__ p2) {
  int rblk = blockIdx.x, tid = threadIdx.x;
  float s = 0;
  for (int k = 0; k < 8; ++k) s += statp[(long)(rblk * 8 + k) * 128 + tid];
  p2[rblk * 128 + tid] = s;
}

__global__ __launch_bounds__(128) void k7b(const float* __restrict__ p2,
                                           const float* __restrict__ g2,
                                           const float* __restrict__ be2,
                                           float* __restrict__ bnB) {
  int tid = threadIdx.x;
  float s = 0;
  for (int k = 0; k < 128; ++k) s += p2[k * 128 + tid];
  __shared__ float sm[128];
  sm[tid] = s;
  __syncthreads();
  if (tid < 64) {
    int oc = tid;
    float mean = sm[oc * 2] * (1.f / 131072.f);
    float var = sm[oc * 2 + 1] * (1.f / 131072.f) - mean * mean;
    float sc = g2[oc] * rsqrtf(fmaxf(var, 0.f) + 1e-5f);
    bnB[oc * 2] = sc;
    bnB[oc * 2 + 1] = be2[oc] - mean * sc;
  }
}

// ---------------- K8: out = relu(relu(bnA(y_init)) + bnB(y2)), NCHW f32 ----------------
__global__ __launch_bounds__(256) void k8_final(const unsigned short* __restrict__ yws,
                                                const unsigned short* __restrict__ y2,
                                                const float* __restrict__ bnA,
                                                const float* __restrict__ bnB,
                                                float* __restrict__ out) {
  __shared__ float tr[64 * 77];
  int tid = threadIdx.x;
  int blk = blockIdx.x;
  int b = blk >> 10, rem = blk & 1023;
  int y = rem >> 2, xq0 = rem & 3;
  int x0 = xq0 * 64;
  int px = tid >> 2, cg = (tid & 3) * 16;
  long prow = (long)b * NP + y * 256 + x0 + px;
  const unsigned short* ysrc = yws + prow * 128 + cg;
  const unsigned short* y2src = y2 + prow * 64 + cg;
  bh8 va = *(const bh8*)ysrc;
  bh8 vb = *(const bh8*)(ysrc + 8);
  bh8 wa = *(const bh8*)y2src;
  bh8 wb = *(const bh8*)(y2src + 8);
#pragma unroll
  for (int j = 0; j < 16; ++j) {
    int c = cg + j;
    unsigned short uy = (unsigned short)(j < 8 ? va[j] : vb[j - 8]);
    unsigned short u2 = (unsigned short)(j < 8 ? wa[j] : wb[j - 8]);
    float iv = fmaxf(b2f(uy) * bnA[c * 2] + bnA[c * 2 + 1], 0.f);
    float cv = b2f(u2) * bnB[c * 2] + bnB[c * 2 + 1];
    tr[c * 77 + px] = fmaxf(iv + cv, 0.f);
  }
  __syncthreads();
  int c = tid >> 2, xq = tid & 3;
  float* orow = out + ((long)(b * 64 + c)) * NP + y * 256 + x0 + xq * 16;
  const float* trow = &tr[c * 77 + xq * 16];
#pragma unroll
  for (int j = 0; j < 16; j += 4) {
    float4 v = make_float4(trow[j], trow[j + 1], trow[j + 2], trow[j + 3]);
    *(float4*)(orow + j) = v;
  }
}

extern "C" void kernel_launch(void* const* d_in, const int* in_sizes, int n_in,
                              void* d_out, int out_size, void* d_ws, size_t ws_size,
                              hipStream_t stream) {
  if (ws_size < (size_t)WS_NEED) return;
  const float* x_i  = (const float*)d_in[0];
  const float* x_e  = (const float*)d_in[1];
  const float* y    = (const float*)d_in[2];
  const float* temp = (const float*)d_in[3];
  const float* wq   = (const float*)d_in[4];
  const float* bq   = (const float*)d_in[5];
  const float* wk   = (const float*)d_in[6];
  const float* bk   = (const float*)d_in[7];
  const float* wv   = (const float*)d_in[8];
  const float* wo   = (const float*)d_in[10];
  const float* w_init = (const float*)d_in[12];
  const float* g_init = (const float*)d_in[14];
  const float* be_init= (const float*)d_in[15];
  const float* w1   = (const float*)d_in[16];
  const float* g1   = (const float*)d_in[18];
  const float* be1  = (const float*)d_in[19];
  const float* w2   = (const float*)d_in[20];
  const float* g2   = (const float*)d_in[22];
  const float* be2  = (const float*)d_in[23];

  char* ws = (char*)d_ws;
  float* gp    = (float*)(ws + WSO_GP);
  float* Mw    = (float*)(ws + WSO_M);
  float* Sw    = (float*)(ws + WSO_S);
  float* attnW = (float*)(ws + WSO_P);
  float* Gw    = (float*)(ws + WSO_G);
  float* wtapT = (float*)(ws + WSO_WTT);
  unsigned short* wBA = (unsigned short*)(ws + WSO_WBA);
  unsigned short* wBB = (unsigned short*)(ws + WSO_WBB);
  unsigned short* xtw = (unsigned short*)(ws + WSO_XT);
  unsigned short* yws = (unsigned short*)(ws + WSO_Y);
  float* statA = (float*)(ws + WSO_STATA);
  float* p2A   = (float*)(ws + WSO_P2A);
  float* bnA   = (float*)(ws + WSO_BNA);
  unsigned short* y2w = (unsigned short*)(ws + WSO_Y2);
  float* statB = (float*)(ws + WSO_STATB);
  float* p2B   = (float*)(ws + WSO_P2B);
  float* bnB   = (float*)(ws + WSO_BNB);
  float* out   = (float*)d_out;

  hipLaunchKernelGGL(k0_prep, dim3(1024), dim3(256), 0, stream,
                     w_init, w1, w2, wtapT, wBB);
  hipLaunchKernelGGL(k1_gram, dim3(128, 2), dim3(512), 0, stream, x_i, x_e, y, gp);
  hipLaunchKernelGGL(k1_reduce, dim3(162), dim3(256), 0, stream, gp, Mw, Sw);
  hipLaunchKernelGGL(k2_attn, dim3(4, 2), dim3(256), 0, stream,
                     Mw, Sw, wq, wk, bq, bk, temp, attnW);
  hipLaunchKernelGGL(k2_g, dim3(4, 2), dim3(256), 0, stream, attnW, wo, wv, Gw);
  hipLaunchKernelGGL(k3_xt, dim3(1024, 2), dim3(256), 0, stream, x_i, x_e, xtw);
  hipLaunchKernelGGL(k3_wprep, dim3(9, 2, 8), dim3(256), 0, stream, wtapT, Gw, wBA);
  hipLaunchKernelGGL(k4_mfma, dim3(1024), dim3(256), 0, stream, xtw, wBA, yws, statA);
  hipLaunchKernelGGL(k5a, dim3(128), dim3(256), 0, stream, statA, p2A);
  hipLaunchKernelGGL(k5b, dim3(1), dim3(256), 0, stream, p2A, g_init, be_init, g1, be1, bnA);
  hipLaunchKernelGGL(k6_mfma, dim3(1024), dim3(256), 0, stream, yws, wBB, bnA, y2w, statB);
  hipLaunchKernelGGL(k7a, dim3(128), dim3(128), 0, stream, statB, p2B);
  hipLaunchKernelGGL(k7b, dim3(1), dim3(128), 0, stream, p2B, g2, be2, bnB);
  hipLaunchKernelGGL(k8_final, dim3(2048), dim3(256), 0, stream, yws, y2w, bnA, bnB, out);
}

// Round 12
// 191.379 us; speedup vs baseline: 1.2559x; 1.2559x over previous
//
#include <hip/hip_runtime.h>
#include <hip/hip_bf16.h>

#define DI __device__ __forceinline__

typedef __attribute__((ext_vector_type(8))) short bh8;
typedef __attribute__((ext_vector_type(4))) float f4;

constexpr int  NP        = 65536;              // H*W per batch
constexpr long GP_STRIDE = 20672;              // 5*4096 + 192

// workspace byte offsets
constexpr long WSO_GP    = 0;                                  // [2][128][GP_STRIDE] f32
constexpr long WSO_M     = WSO_GP    + 2L*128*GP_STRIDE*4;     // [2][5][4096] f32
constexpr long WSO_S     = WSO_M     + 2L*5*4096*4;            // [2][192] f32
constexpr long WSO_P     = WSO_S     + 2L*192*4;               // attn [2][2][64][8] f32 (reuse)
constexpr long WSO_QK    = WSO_P     + 2L*5*4096*4;            // unused
constexpr long WSO_G     = WSO_QK    + 2L*2*4096*4;            // [2][2][4096] f32
constexpr long WSO_WKT   = WSO_G     + 2L*2*4096*4;            // unused
constexpr long WSO_WTT   = WSO_WKT   + 4096L*4;                // [9][192][128] f32 (wtapT)
constexpr long WSO_WBA   = WSO_WTT   + 221184L*4;              // [2][36][128][32] bf16 (UNswizzled)
constexpr long WSO_WBB   = WSO_WBA   + 2L*36*4096*2;           // [18][64][32] bf16 (UNswizzled)
constexpr long WSO_XT    = WSO_WBB   + 36864L*2;               // [2][NP][128] bf16 pixel-major [xi;xe]
constexpr long WSO_Y     = WSO_XT    + 2L*NP*128*2;            // [2][NP][128] bf16 pixel-major
constexpr long WSO_STATA = WSO_Y     + 2L*NP*128*2;            // [1024][256] f32
constexpr long WSO_P2A   = WSO_STATA + 1024L*256*4;            // [128][256] f32
constexpr long WSO_BNA   = WSO_P2A   + 128L*256*4;             // [256] f32
constexpr long WSO_Y2    = WSO_BNA   + 256L*4;                 // [2][NP][64] bf16 pixel-major
constexpr long WSO_STATB = WSO_Y2    + 2L*NP*64*2;             // [1024][128] f32
constexpr long WSO_P2B   = WSO_STATB + 1024L*128*4;            // [128][128] f32
constexpr long WSO_BNB   = WSO_P2B   + 128L*128*4;             // [128] f32
constexpr long WS_NEED   = WSO_BNB   + 128L*4;

constexpr int AROWB = 136 * 128;   // bytes per row-strip in conv LDS (136 px * 128 B)
constexpr int ALDSB = 3 * AROWB;   // 52224

DI float b2f(unsigned short u) { return __uint_as_float(((unsigned)u) << 16); }
DI unsigned short f2b(float f) {
  __hip_bfloat16 h = __float2bfloat16(f);
  return *(unsigned short*)&h;
}
DI void gl_lds16(const void* g, void* l) {
  __builtin_amdgcn_global_load_lds(
      (const __attribute__((address_space(1))) unsigned int*)g,
      (__attribute__((address_space(3))) unsigned int*)l, 16, 0, 0);
}

// NOTE: parameter names must not collide with .x/.y/.z/.w member tokens
#define FMA4(acc, S_, V_)                                                      \
  acc.x = fmaf(S_, V_.x, acc.x); acc.y = fmaf(S_, V_.y, acc.y);                \
  acc.z = fmaf(S_, V_.z, acc.z); acc.w = fmaf(S_, V_.w, acc.w);

// ---------------- K0: static weight re-layouts (wtapT + conv B) ----------------
__global__ __launch_bounds__(256) void k0_prep(const float* __restrict__ w_init,
                                               const float* __restrict__ w1,
                                               const float* __restrict__ w2,
                                               float* __restrict__ wtapT,
                                               unsigned short* __restrict__ wBB) {
  int i = blockIdx.x * 256 + threadIdx.x;
  if (i < 221184) {                 // wtapT[tap][cin][oc]
    int tap = i / 24576;
    int rem = i % 24576;
    int cin = rem >> 7, oc = rem & 127;
    float v = (oc < 64) ? w_init[(oc * 192 + cin) * 9 + tap]
                        : w1[((oc - 64) * 192 + cin) * 9 + tap];
    wtapT[i] = v;
  } else if (i < 258048) {          // conv B weights: step = tap*2 + s  (UNswizzled)
    int j = i - 221184;
    int step = j >> 11;
    int rem = j & 2047;
    int oc = rem >> 5, kk = rem & 31;
    int tap = step >> 1, s = step & 1;
    int c = s * 32 + kk;
    wBB[(step << 11) + (oc << 5) + kk] = f2b(w2[(oc * 64 + c) * 9 + tap]);
  }
}

// ---------------- K1: per-b Gram matrices via MFMA (hi/lo bf16 split) ----------------
__global__ __launch_bounds__(512, 2) void k1_gram(const float* __restrict__ xi,
                                                  const float* __restrict__ xe,
                                                  const float* __restrict__ yy,
                                                  float* __restrict__ gp) {
  __shared__ alignas(16) char lds[2 * 49152];   // dbuf x [3t][2p][64c][128B] swizzled
  int tid = threadIdx.x;
  int lane = tid & 63, wave = tid >> 6;
  int i_t = wave & 3, jh = wave >> 2;
  int blk = blockIdx.x, b = blockIdx.y;
  const float* srcs[3];
  srcs[0] = yy + (long)b * 64 * NP;
  srcs[1] = xe + (long)b * 64 * NP;
  srcs[2] = xi + (long)b * 64 * NP;

  f4 zero = {0.f, 0.f, 0.f, 0.f};
  f4 acc[5][2];
#pragma unroll
  for (int g = 0; g < 5; ++g) { acc[g][0] = zero; acc[g][1] = zero; }
  float rs[6] = {0.f, 0.f, 0.f, 0.f, 0.f, 0.f};

  int rowv[6], col4v[6], tv[6], cv[6];
#pragma unroll
  for (int ii = 0; ii < 6; ++ii) {
    int li = ii * 512 + tid;
    rowv[ii] = li >> 4; col4v[ii] = li & 15;
    tv[ii] = rowv[ii] >> 6; cv[ii] = rowv[ii] & 63;
  }

  float4 v[6];
#define LOADS(S)                                                                \
  { int n0 = blk * 512 + (S) * 64;                                              \
    _Pragma("unroll") for (int ii = 0; ii < 6; ++ii)                            \
      v[ii] = *(const float4*)(srcs[tv[ii]] + (long)cv[ii] * NP + n0 + col4v[ii] * 4); }
#define CVTW(BUF)                                                               \
  { _Pragma("unroll") for (int ii = 0; ii < 6; ++ii) {                          \
      rs[ii] += v[ii].x + v[ii].y + v[ii].z + v[ii].w;                          \
      ushort4 hi, lo;                                                           \
      hi.x = f2b(v[ii].x); lo.x = f2b(v[ii].x - b2f(hi.x));                     \
      hi.y = f2b(v[ii].y); lo.y = f2b(v[ii].y - b2f(hi.y));                     \
      hi.z = f2b(v[ii].z); lo.z = f2b(v[ii].z - b2f(hi.z));                     \
      hi.w = f2b(v[ii].w); lo.w = f2b(v[ii].w - b2f(hi.w));                     \
      int base = (BUF) * 49152 + (tv[ii] * 2 * 64 + cv[ii]) * 128;              \
      int colo = (col4v[ii] * 8) ^ ((cv[ii] & 7) << 4);                         \
      *(ushort4*)(lds + base + colo) = hi;                                      \
      *(ushort4*)(lds + base + 8192 + colo) = lo; } }

  LOADS(0)
  CVTW(0)
  for (int s = 0; s < 8; ++s) {
    int buf = s & 1;
    __syncthreads();
    if (s < 7) LOADS(s + 1)     // issued post-barrier: hide under ds_read+MFMA
    const char* lb = lds + buf * 49152;
#pragma unroll
    for (int kk = 0; kk < 2; ++kk) {
      bh8 ah[3], al[3];
#pragma unroll
      for (int t = 0; t < 3; ++t) {
        int cc = i_t * 16 + (lane & 15);
        int col = (kk * 64 + ((lane >> 4) << 4)) ^ ((cc & 7) << 4);
        ah[t] = *(const bh8*)(lb + ((t * 2) * 64 + cc) * 128 + col);
        al[t] = *(const bh8*)(lb + ((t * 2) * 64 + cc) * 128 + 8192 + col);
      }
#pragma unroll
      for (int jj = 0; jj < 2; ++jj) {
        int j = jh * 2 + jj;
        bh8 bh_[3], bl_[3];
#pragma unroll
        for (int t = 0; t < 3; ++t) {
          int dd = j * 16 + (lane & 15);
          int col = (kk * 64 + ((lane >> 4) << 4)) ^ ((dd & 7) << 4);
          bh_[t] = *(const bh8*)(lb + ((t * 2) * 64 + dd) * 128 + col);
          bl_[t] = *(const bh8*)(lb + ((t * 2) * 64 + dd) * 128 + 8192 + col);
        }
#define GRAM(G, TA, TB)                                                            \
        acc[G][jj] = __builtin_amdgcn_mfma_f32_16x16x32_bf16(ah[TA], bh_[TB], acc[G][jj], 0, 0, 0); \
        acc[G][jj] = __builtin_amdgcn_mfma_f32_16x16x32_bf16(ah[TA], bl_[TB], acc[G][jj], 0, 0, 0); \
        acc[G][jj] = __builtin_amdgcn_mfma_f32_16x16x32_bf16(al[TA], bh_[TB], acc[G][jj], 0, 0, 0);
        GRAM(0, 0, 1) GRAM(1, 0, 2) GRAM(2, 0, 0) GRAM(3, 1, 1) GRAM(4, 2, 2)
#undef GRAM
      }
    }
    if (s < 7) CVTW(buf ^ 1)
  }
#undef LOADS
#undef CVTW

  float* outp = gp + ((long)b * 128 + blk) * GP_STRIDE;
#pragma unroll
  for (int g = 0; g < 5; ++g)
#pragma unroll
    for (int jj = 0; jj < 2; ++jj) {
      int j = jh * 2 + jj;
#pragma unroll
      for (int r = 0; r < 4; ++r) {
        int cg = i_t * 16 + ((lane >> 4) << 2) + r;
        int dg = j * 16 + (lane & 15);
        outp[g * 4096 + cg * 64 + dg] = acc[g][jj][r];
      }
    }
#pragma unroll
  for (int ii = 0; ii < 6; ++ii) {
    float s = rs[ii];
    s += __shfl_xor(s, 1); s += __shfl_xor(s, 2);
    s += __shfl_xor(s, 4); s += __shfl_xor(s, 8);
    if ((lane & 15) == 0) outp[5 * 4096 + rowv[ii]] = s;
  }
}

// ---------------- K1r: reduce Gram partials ----------------
__global__ __launch_bounds__(256) void k1_reduce(const float* __restrict__ gp,
                                                 float* __restrict__ M,
                                                 float* __restrict__ S) {
  int i = blockIdx.x * 256 + threadIdx.x;
  if (i >= 2 * GP_STRIDE) return;
  int b = i / GP_STRIDE, o = i % GP_STRIDE;
  const float* p = gp + (long)b * 128 * GP_STRIDE + o;
  float s = 0;
  for (int k = 0; k < 128; ++k) s += p[(long)k * GP_STRIDE];
  if (o < 20480) M[b * 20480 + o] = s;
  else           S[b * 192 + (o - 20480)] = s;
}

// ---------------- K2a: row-split attention front-end (grid 4x2) ----------------
__global__ __launch_bounds__(256) void k2_attn(const float* __restrict__ M,
                                               const float* __restrict__ Ssum,
                                               const float* __restrict__ wq,
                                               const float* __restrict__ wk,
                                               const float* __restrict__ bq,
                                               const float* __restrict__ bk,
                                               const float* __restrict__ temp,
                                               float* __restrict__ attnG) {
  __shared__ float Ms[5 * 4096];       // all five M matrices (80 KB)
  __shared__ float WQr[16 * 68];
  __shared__ float WKr[16 * 68];
  __shared__ float Ps[16 * 68];
  __shared__ float QKs[16 * 17];
  __shared__ float Ss[192], bqs[16], bks[16], tt[2];
  __shared__ float uu[16], ve[16], vi[16];
  __shared__ float dqv[16], dkev[16], dkiv[16];
  __shared__ float nqs[16], nkes[16], nkis[16];

  int r = blockIdx.x, b = blockIdx.y, tid = threadIdx.x;
  int i0 = r * 16;
  const float* Mb = M + b * 20480;
#pragma unroll
  for (int it = 0; it < 20; ++it) {
    int slot = it * 256 + tid;
    *(float4*)&Ms[slot * 4] = *(const float4*)(Mb + slot * 4);
  }
  {
    int row = tid >> 4, c4 = (tid & 15) * 4;
    *(float4*)&WQr[row * 68 + c4] = *(const float4*)(wq + (i0 + row) * 64 + c4);
    *(float4*)&WKr[row * 68 + c4] = *(const float4*)(wk + (i0 + row) * 64 + c4);
  }
  if (tid < 192) Ss[tid] = Ssum[b * 192 + tid];
  else if (tid < 208) bqs[tid - 192] = bq[i0 + tid - 192];
  else if (tid < 224) bks[tid - 208] = bk[i0 + tid - 208];
  else if (tid < 226) tt[tid - 224] = temp[2 * r + (tid - 224)];
  __syncthreads();

  int il = tid >> 4, q = tid & 15, j0 = q * 4;
  {
    float4 a = *(const float4*)&WQr[il * 68 + j0];
    float4 c = *(const float4*)&WKr[il * 68 + j0];
    float pu = a.x * Ss[j0] + a.y * Ss[j0 + 1] + a.z * Ss[j0 + 2] + a.w * Ss[j0 + 3];
    float pe = c.x * Ss[64 + j0] + c.y * Ss[64 + j0 + 1] + c.z * Ss[64 + j0 + 2] + c.w * Ss[64 + j0 + 3];
    float pi = c.x * Ss[128 + j0] + c.y * Ss[128 + j0 + 1] + c.z * Ss[128 + j0 + 2] + c.w * Ss[128 + j0 + 3];
#pragma unroll
    for (int m = 1; m <= 8; m <<= 1) {
      pu += __shfl_xor(pu, m); pe += __shfl_xor(pe, m); pi += __shfl_xor(pi, m);
    }
    if (q == 0) { uu[il] = pu; ve[il] = pe; vi[il] = pi; }
  }
  // diagonal quadratic forms d = w_i^T M_g w_i for g = 2,3,4
#pragma unroll
  for (int t = 0; t < 3; ++t) {
    const float* W = (t == 0) ? WQr : WKr;
    const float* Mg = &Ms[(2 + t) * 4096];
    float4 t4 = {0.f, 0.f, 0.f, 0.f};
    for (int k4 = 0; k4 < 64; k4 += 4) {
      float4 w4 = *(const float4*)&W[il * 68 + k4];
      float4 m0 = *(const float4*)&Mg[(k4 + 0) * 64 + j0];
      float4 m1 = *(const float4*)&Mg[(k4 + 1) * 64 + j0];
      float4 m2 = *(const float4*)&Mg[(k4 + 2) * 64 + j0];
      float4 m3 = *(const float4*)&Mg[(k4 + 3) * 64 + j0];
      FMA4(t4, w4.x, m0) FMA4(t4, w4.y, m1) FMA4(t4, w4.z, m2) FMA4(t4, w4.w, m3)
    }
    float4 wj = *(const float4*)&W[il * 68 + j0];
    float d = t4.x * wj.x + t4.y * wj.y + t4.z * wj.z + t4.w * wj.w;
#pragma unroll
    for (int m = 1; m <= 8; m <<= 1) d += __shfl_xor(d, m);
    if (q == 0) {
      if (t == 0) dqv[il] = d; else if (t == 1) dkev[il] = d; else dkiv[il] = d;
    }
  }
  __syncthreads();
  if (tid < 16) {
    const float N = 65536.f;
    float bqi = bqs[tid], bki = bks[tid];
    nqs[tid]  = fmaxf(sqrtf(fmaxf(dqv[tid]  + 2.f * uu[tid] * bqi + N * bqi * bqi, 0.f)), 1e-12f);
    nkes[tid] = fmaxf(sqrtf(fmaxf(dkev[tid] + 2.f * ve[tid] * bki + N * bki * bki, 0.f)), 1e-12f);
    nkis[tid] = fmaxf(sqrtf(fmaxf(dkiv[tid] + 2.f * vi[tid] * bki + N * bki * bki, 0.f)), 1e-12f);
  }
  __syncthreads();

  for (int v = 0; v < 2; ++v) {
    const float* Mg = &Ms[v * 4096];
    float4 p4 = {0.f, 0.f, 0.f, 0.f};
    for (int k4 = 0; k4 < 64; k4 += 4) {
      float4 w4 = *(const float4*)&WQr[il * 68 + k4];
      float4 m0 = *(const float4*)&Mg[(k4 + 0) * 64 + j0];
      float4 m1 = *(const float4*)&Mg[(k4 + 1) * 64 + j0];
      float4 m2 = *(const float4*)&Mg[(k4 + 2) * 64 + j0];
      float4 m3 = *(const float4*)&Mg[(k4 + 3) * 64 + j0];
      FMA4(p4, w4.x, m0) FMA4(p4, w4.y, m1) FMA4(p4, w4.z, m2) FMA4(p4, w4.w, m3)
    }
    *(float4*)&Ps[il * 68 + j0] = p4;
    __syncthreads();
    {
      int i2 = tid >> 4, jl = tid & 15;
      float s = 0.f;
      for (int k4 = 0; k4 < 64; k4 += 4) {
        float4 pp = *(const float4*)&Ps[i2 * 68 + k4];
        float4 kk = *(const float4*)&WKr[jl * 68 + k4];
        s += pp.x * kk.x + pp.y * kk.y + pp.z * kk.z + pp.w * kk.w;
      }
      QKs[i2 * 17 + jl] = s;
    }
    __syncthreads();
    if (tid < 128) {
      int i2 = tid >> 3, d = tid & 7;
      int h2 = i2 >> 3;
      int jl = h2 * 8 + d;
      float vx = v ? vi[jl] : ve[jl];
      float nk = v ? nkis[jl] : nkes[jl];
      float bqi = bqs[i2], bkj = bks[jl];
      float val = QKs[i2 * 17 + jl] + uu[i2] * bkj + bqi * vx + 65536.f * bqi * bkj;
      val = val / (nqs[i2] * nk) * tt[h2];
      float mx = val;
      mx = fmaxf(mx, __shfl_xor(mx, 1));
      mx = fmaxf(mx, __shfl_xor(mx, 2));
      mx = fmaxf(mx, __shfl_xor(mx, 4));
      float ex = expf(val - mx);
      float se = ex;
      se += __shfl_xor(se, 1); se += __shfl_xor(se, 2); se += __shfl_xor(se, 4);
      attnG[((long)(b * 2 + v) * 64 + i0 + i2) * 8 + d] = ex / se;
    }
    __syncthreads();
  }
}

// ---------------- K2b: row-split G = wo . BD(attn) . wv (grid 4x2) ----------------
__global__ __launch_bounds__(256) void k2_g(const float* __restrict__ attnG,
                                            const float* __restrict__ wo,
                                            const float* __restrict__ wv,
                                            float* __restrict__ G) {
  __shared__ float WVs[4096];
  __shared__ float WOr[16 * 68];
  __shared__ float As[2 * 64 * 12];
  __shared__ float Gm[16 * 68];
  int ro = blockIdx.x, b = blockIdx.y, tid = threadIdx.x;
  int o0 = ro * 16;
#pragma unroll
  for (int it = 0; it < 4; ++it) {
    int slot = it * 256 + tid;
    *(float4*)&WVs[slot * 4] = *(const float4*)(wv + slot * 4);
  }
  {
    int row = tid >> 4, c4 = (tid & 15) * 4;
    *(float4*)&WOr[row * 68 + c4] = *(const float4*)(wo + (o0 + row) * 64 + c4);
  }
#pragma unroll
  for (int it = 0; it < 4; ++it) {
    int slot = it * 256 + tid;     // 1024 = 2v * 64row * 8d
    int v = slot >> 9, rr = (slot >> 3) & 63, d = slot & 7;
    As[v * 768 + rr * 12 + d] = attnG[((long)(b * 2 + v) * 64 + rr) * 8 + d];
  }
  __syncthreads();
  int ol = tid >> 4, q = tid & 15, j0 = q * 4;
  int h = q >> 1, dbase = (q & 1) * 4;
  for (int v = 0; v < 2; ++v) {
    float4 g4 = {0.f, 0.f, 0.f, 0.f};
#pragma unroll
    for (int c = 0; c < 8; ++c) {
      float w = WOr[ol * 68 + h * 8 + c];
      float4 a4 = *(const float4*)&As[v * 768 + (h * 8 + c) * 12 + dbase];
      FMA4(g4, w, a4)
    }
    *(float4*)&Gm[ol * 68 + j0] = g4;
    __syncthreads();
    float4 a4 = {0.f, 0.f, 0.f, 0.f};
    for (int m4 = 0; m4 < 64; m4 += 4) {
      float4 gm4 = *(const float4*)&Gm[ol * 68 + m4];
      float4 r0 = *(const float4*)&WVs[(m4 + 0) * 64 + j0];
      float4 r1 = *(const float4*)&WVs[(m4 + 1) * 64 + j0];
      float4 r2 = *(const float4*)&WVs[(m4 + 2) * 64 + j0];
      float4 r3 = *(const float4*)&WVs[(m4 + 3) * 64 + j0];
      FMA4(a4, gm4.x, r0) FMA4(a4, gm4.y, r1) FMA4(a4, gm4.z, r2) FMA4(a4, gm4.w, r3)
    }
    *(float4*)(G + ((long)(b * 2 + v)) * 4096 + (o0 + ol) * 64 + j0) = a4;
    __syncthreads();
  }
}

// ---------------- K3t: transpose x_i,x_e -> [b][px][128ch] bf16 pixel-major ----------------
__global__ __launch_bounds__(256) void k3_xt(const float* __restrict__ xi,
                                             const float* __restrict__ xe,
                                             unsigned short* __restrict__ xt) {
  __shared__ float st[2][64][66];
  int tid = threadIdx.x;
  int b = blockIdx.y;
  int px0 = blockIdx.x * 64;
  for (int it = 0; it < 8; ++it) {
    int slot = it * 256 + tid;          // 2048 = 2t * 64c * 16 float4
    int t = slot >> 10, r = slot & 1023, c = r >> 4, j = r & 15;
    const float* s = (t ? xe : xi) + ((long)b * 64 + c) * NP + px0 + j * 4;
    float4 v = *(const float4*)s;
    st[t][j * 4 + 0][c] = v.x;
    st[t][j * 4 + 1][c] = v.y;
    st[t][j * 4 + 2][c] = v.z;
    st[t][j * 4 + 3][c] = v.w;
  }
  __syncthreads();
  unsigned short* xb = xt + ((long)b * NP + px0) * 128;
  for (int it = 0; it < 4; ++it) {
    int slot = it * 256 + tid;          // 1024 = 64px * 16 chunks(8ch)
    int px = slot >> 4, c8 = slot & 15;
    int t = c8 >> 3, cb = (c8 & 7) * 8;
    bh8 o;
#pragma unroll
    for (int e = 0; e < 8; ++e) o[e] = (short)f2b(st[t][px][cb + e]);
    *(bh8*)(xb + (long)px * 128 + c8 * 8) = o;
  }
}

// ---------------- K3w: composed conv-A weights W'_b = Wcat . Gstack_b (bf16, UNswizzled) ----------------
__global__ __launch_bounds__(256) void k3_wprep(const float* __restrict__ wtapT,
                                                const float* __restrict__ G,
                                                unsigned short* __restrict__ wBA) {
  __shared__ float Gs[2][64][8];    // [variant e/i][row j][cn-local]
  int tid = threadIdx.x;
  int tap = blockIdx.x, b = blockIdx.y, g = blockIdx.z;
  const float* Gb = G + (long)b * 2 * 4096;
  for (int it = 0; it < 4; ++it) {
    int slot = it * 256 + tid;        // 1024 = 2v * 64j * 8e
    int v = slot >> 9, r = slot & 511, j = r >> 3, e = r & 7;
    Gs[v][j][e] = Gb[v * 4096 + j * 64 + g * 8 + e];
  }
  __syncthreads();
  int h = tid >> 7, oc = tid & 127;
  const float* wt = wtapT + (long)tap * 24576;
  float acc[8] = {0.f, 0.f, 0.f, 0.f, 0.f, 0.f, 0.f, 0.f};
  if (h == 0) {
    for (int j = 0; j < 64; ++j) {
      float w0 = wt[j * 128 + oc];
      float w2v = wt[(128 + j) * 128 + oc];
      const float* ge = &Gs[0][j][0];
      const float* gi = &Gs[1][j][0];
#pragma unroll
      for (int e = 0; e < 8; ++e) acc[e] += w0 * ge[e] + w2v * gi[e];
    }
  } else {
    for (int j = 0; j < 64; ++j) {
      float w0 = wt[(64 + j) * 128 + oc];
      const float* ge = &Gs[0][j][0];
#pragma unroll
      for (int e = 0; e < 8; ++e) acc[e] += w0 * ge[e];
    }
  }
  unsigned short* wb = wBA + (long)b * 36 * 4096;
  int s = g >> 2;
  int step = h * 18 + tap * 2 + s;
#pragma unroll
  for (int e = 0; e < 8; ++e) {
    int kk = (g & 3) * 8 + e;
    wb[step * 4096 + oc * 32 + kk] = f2b(acc[e]);
  }
}

// ---------------- K4: conv3x3 128->128 MFMA, B in regs, A-frag reg double-buffer ----------------
__global__ __launch_bounds__(256, 2) void k4_mfma(const unsigned short* __restrict__ xt,
                                                  const unsigned short* __restrict__ wBA,
                                                  unsigned short* __restrict__ yout,
                                                  float* __restrict__ statp) {
  __shared__ alignas(16) char lds[ALDSB + 1024];
  float* statf = (float*)(lds + ALDSB);

  int tid = threadIdx.x;
  int wave = tid >> 6, lane = tid & 63;
  int kc = lane >> 4, i16 = lane & 15;

  int bid = blockIdx.x;
  int blk = (bid & 7) * 128 + (bid >> 3);   // bijective XCD swizzle (1024 % 8 == 0)
  int b = blk >> 9, y = (blk >> 1) & 255, xtile = blk & 1;
  int x0 = xtile << 7;
  int rows[3] = {y > 0 ? y - 1 : 1, y, y < 255 ? y + 1 : 254};

  const unsigned short* fb = xt + (long)b * NP * 128;
  const char* wBAb = (const char*)(wBA + (long)b * 36 * 4096);
  statf[tid] = 0.f;

  int wm = wave & 1, wn = wave >> 1;
  int m0 = wm * 64, n0 = wn * 64;
  int boff = (n0 + i16) * 64 + kc * 16;     // per-lane B byte offset within a step

  f4 zero = {0.f, 0.f, 0.f, 0.f};
  f4 acc[4][4];
#pragma unroll
  for (int i = 0; i < 4; ++i)
#pragma unroll
    for (int j = 0; j < 4; ++j) acc[i][j] = zero;

#define LOADB4(ST, BF)                                                         \
  { const char* wsrc_ = wBAb + (long)(ST) * 8192 + boff;                       \
    BF[0] = *(const bh8*)(wsrc_);                                              \
    BF[1] = *(const bh8*)(wsrc_ + 1024);                                       \
    BF[2] = *(const bh8*)(wsrc_ + 2048);                                       \
    BF[3] = *(const bh8*)(wsrc_ + 3072); }

#define AFLOAD(STL, AF)                                                        \
  { int tap_ = (STL) >> 1, s_ = (STL) & 1;                                     \
    int kx_ = tap_ % 3, rowk_ = tap_ / 3;                                      \
    const char* arow_ = lds + rowk_ * AROWB;                                   \
    int cbb_ = s_ * 64 + kc * 16;                                              \
    _Pragma("unroll") for (int mf = 0; mf < 4; ++mf) {                         \
      int pxl_ = kx_ + m0 + mf * 16 + i16;                                     \
      AF[mf] = *(const bh8*)(arow_ + pxl_ * 128 + (cbb_ ^ ((pxl_ & 7) << 4))); \
    } }

#define MFMA16(AF, BF)                                                         \
  { _Pragma("unroll") for (int mf = 0; mf < 4; ++mf)                           \
      _Pragma("unroll") for (int nf = 0; nf < 4; ++nf)                         \
        acc[mf][nf] = __builtin_amdgcn_mfma_f32_16x16x32_bf16(AF[mf], BF[nf], acc[mf][nf], 0, 0, 0); }

// issue next step's A reads BEFORE this step's MFMAs, then refill B
#define STEPP(STL, ACUR, ANXT, BCUR)                                           \
  { if ((STL) < 17) AFLOAD((STL) + 1, ANXT)                                    \
    MFMA16(ACUR, BCUR)                                                         \
    if (stb + (STL) + 3 < 36) LOADB4(stb + (STL) + 3, BCUR) }

  bh8 B0[4], B1[4], B2[4];
  LOADB4(0, B0)
  LOADB4(1, B1)
  LOADB4(2, B2)

  bh8 A0[4], A1[4];
  for (int ch = 0; ch < 2; ++ch) {
    __syncthreads();                        // prior chunk readers done
#pragma unroll
    for (int it = 0; it < 13; ++it) {
      int base = (wave * 13 + it) << 10;
      if (base < ALDSB) {
        int slot = base + lane * 16;
        int row = slot / AROWB;
        int rr = slot - row * AROWB;
        int px = rr >> 7, cb = rr & 127;
        int pxl = px < 130 ? px : 129;
        int gx = x0 - 1 + pxl;
        gx = gx < 0 ? 1 : (gx > 255 ? 254 : gx);
        int cbs = cb ^ ((px & 7) << 4);
        const char* src = (const char*)(fb + (long)(rows[row] * 256 + gx) * 128 + ch * 64) + cbs;
        gl_lds16(src, lds + base);
      }
    }
    __syncthreads();                        // A staged

    int stb = ch * 18;
    AFLOAD(0, A0)
    STEPP(0,  A0, A1, B0)
    STEPP(1,  A1, A0, B1)
    STEPP(2,  A0, A1, B2)
    STEPP(3,  A1, A0, B0)
    STEPP(4,  A0, A1, B1)
    STEPP(5,  A1, A0, B2)
    STEPP(6,  A0, A1, B0)
    STEPP(7,  A1, A0, B1)
    STEPP(8,  A0, A1, B2)
    STEPP(9,  A1, A0, B0)
    STEPP(10, A0, A1, B1)
    STEPP(11, A1, A0, B2)
    STEPP(12, A0, A1, B0)
    STEPP(13, A1, A0, B1)
    STEPP(14, A0, A1, B2)
    STEPP(15, A1, A0, B0)
    STEPP(16, A0, A1, B1)
    STEPP(17, A1, A0, B2)
  }
#undef LOADB4
#undef AFLOAD
#undef MFMA16
#undef STEPP

#pragma unroll
  for (int nf = 0; nf < 4; ++nf) {
    float s1 = 0.f, s2 = 0.f;
#pragma unroll
    for (int mf = 0; mf < 4; ++mf)
#pragma unroll
      for (int r = 0; r < 4; ++r) {
        float v = acc[mf][nf][r];
        s1 += v; s2 += v * v;
      }
    s1 += __shfl_xor(s1, 16); s2 += __shfl_xor(s2, 16);
    s1 += __shfl_xor(s1, 32); s2 += __shfl_xor(s2, 32);
    if (lane < 16) {
      int oc = n0 + nf * 16 + i16;
      atomicAdd(&statf[oc * 2], s1);
      atomicAdd(&statf[oc * 2 + 1], s2);
    }
  }
  __syncthreads();
#pragma unroll
  for (int nf = 0; nf < 4; ++nf) {
    int oc2 = (n0 + nf * 16 + i16) * 2;
#pragma unroll
    for (int mf = 0; mf < 4; ++mf)
#pragma unroll
      for (int r = 0; r < 4; ++r) {
        int px = m0 + mf * 16 + kc * 4 + r;
        *(unsigned short*)(lds + px * 256 + (oc2 ^ ((px & 7) << 4))) = f2b(acc[mf][nf][r]);
      }
  }
  __syncthreads();
  unsigned short* yb = yout + (long)b * NP * 128;
#pragma unroll
  for (int it = 0; it < 8; ++it) {
    int slot = (it * 256 + tid) * 16;
    int px = slot >> 8, cb = slot & 255;
    int cbs = cb ^ ((px & 7) << 4);
    f4 v = *(const f4*)(lds + px * 256 + cbs);
    *(f4*)((char*)(yb + (long)(y * 256 + x0 + px) * 128) + cb) = v;
  }
  statp[(long)bid * 256 + tid] = statf[tid];
}

// ---------------- K5a/K5b: BN stat reduce (conv A) ----------------
__global__ __launch_bounds__(256) void k5a(const float* __restrict__ statp, float* __restrict__ p2) {
  int rblk = blockIdx.x, tid = threadIdx.x;
  float s = 0;
  for (int k = 0; k < 8; ++k) s += statp[(long)(rblk * 8 + k) * 256 + tid];
  p2[rblk * 256 + tid] = s;
}

__global__ __launch_bounds__(256) void k5b(const float* __restrict__ p2,
                                           const float* __restrict__ g_init,
                                           const float* __restrict__ be_init,
                                           const float* __restrict__ g1,
                                           const float* __restrict__ be1,
                                           float* __restrict__ bnA) {
  int tid = threadIdx.x;
  float s = 0;
  for (int k = 0; k < 128; ++k) s += p2[k * 256 + tid];
  __shared__ float sm[256];
  sm[tid] = s;
  __syncthreads();
  if (tid < 128) {
    int oc = tid;
    float mean = sm[oc * 2] * (1.f / 131072.f);
    float var = sm[oc * 2 + 1] * (1.f / 131072.f) - mean * mean;
    float g  = oc < 64 ? g_init[oc] : g1[oc - 64];
    float be = oc < 64 ? be_init[oc] : be1[oc - 64];
    float sc = g * rsqrtf(fmaxf(var, 0.f) + 1e-5f);
    bnA[oc * 2] = sc;
    bnA[oc * 2 + 1] = be - mean * sc;
  }
}

// ---------------- K6: conv3x3 relu(bn1(y1)) -> 64 MFMA, B in regs, A reg double-buffer ----------------
__global__ __launch_bounds__(256, 2) void k6_mfma(const unsigned short* __restrict__ yws,
                                                  const unsigned short* __restrict__ wBB,
                                                  const float* __restrict__ bnA,
                                                  unsigned short* __restrict__ y2,
                                                  float* __restrict__ statp) {
  __shared__ alignas(16) char lds[ALDSB + 512];
  float* statf = (float*)(lds + ALDSB);

  int tid = threadIdx.x;
  int wave = tid >> 6, lane = tid & 63;
  int kc = lane >> 4, i16 = lane & 15;

  int bid = blockIdx.x;
  int blk = (bid & 7) * 128 + (bid >> 3);
  int b = blk >> 9, y = (blk >> 1) & 255, xtile = blk & 1;
  int x0 = xtile << 7;
  int rows[3] = {y > 0 ? y - 1 : 1, y, y < 255 ? y + 1 : 254};

  if (tid < 128) statf[tid] = 0.f;

  int wm = wave & 1, wn = wave >> 1;
  int m0 = wm * 64, n0 = wn * 32;
  int boff = (n0 + i16) * 64 + kc * 16;

#define LOADB2(ST, BF)                                                         \
  { const char* wsrc_ = (const char*)wBB + (long)(ST) * 4096 + boff;           \
    BF[0] = *(const bh8*)(wsrc_);                                              \
    BF[1] = *(const bh8*)(wsrc_ + 1024); }

  bh8 B0[2], B1[2], B2[2];
  LOADB2(0, B0)
  LOADB2(1, B1)
  LOADB2(2, B2)

  int c0 = (tid & 7) * 8;
  float sc[8], bi[8];
#pragma unroll
  for (int e = 0; e < 8; ++e) {
    int cc = 64 + c0 + e;
    sc[e] = bnA[cc * 2];
    bi[e] = bnA[cc * 2 + 1];
  }
  const unsigned short* yb = yws + (long)b * NP * 128;
  int pbase = tid >> 3;
  for (int r = 0; r < 13; ++r) {
    int p = pbase + r * 32;
    if (p < 408) {
      int row = p / 136, pxs = p - row * 136;
      int pxl = pxs < 130 ? pxs : 129;
      int gx = x0 - 1 + pxl;
      gx = gx < 0 ? 1 : (gx > 255 ? 254 : gx);
      const unsigned short* src = yb + (long)(rows[row] * 256 + gx) * 128 + 64 + c0;
      bh8 v = *(const bh8*)src;
      bh8 o;
#pragma unroll
      for (int e = 0; e < 8; ++e) {
        float f = fmaxf(b2f((unsigned short)v[e]) * sc[e] + bi[e], 0.f);
        o[e] = (short)f2b(f);
      }
      *(bh8*)(lds + p * 128 + ((c0 * 2) ^ ((pxs & 7) << 4))) = o;
    }
  }
  __syncthreads();

  f4 zero = {0.f, 0.f, 0.f, 0.f};
  f4 acc[4][2];
#pragma unroll
  for (int i = 0; i < 4; ++i) { acc[i][0] = zero; acc[i][1] = zero; }

#define AFLOAD6(STL, AF)                                                       \
  { int tap_ = (STL) >> 1, s_ = (STL) & 1;                                     \
    int kx_ = tap_ % 3, rowk_ = tap_ / 3;                                      \
    const char* arow_ = lds + rowk_ * AROWB;                                   \
    int cbb_ = s_ * 64 + kc * 16;                                              \
    _Pragma("unroll") for (int mf = 0; mf < 4; ++mf) {                         \
      int pxl_ = kx_ + m0 + mf * 16 + i16;                                     \
      AF[mf] = *(const bh8*)(arow_ + pxl_ * 128 + (cbb_ ^ ((pxl_ & 7) << 4))); \
    } }

#define MFMA8(AF, BF)                                                          \
  { _Pragma("unroll") for (int mf = 0; mf < 4; ++mf)                           \
      _Pragma("unroll") for (int nf = 0; nf < 2; ++nf)                         \
        acc[mf][nf] = __builtin_amdgcn_mfma_f32_16x16x32_bf16(AF[mf], BF[nf], acc[mf][nf], 0, 0, 0); }

#define STEPP6(STL, ACUR, ANXT, BCUR)                                          \
  { if ((STL) < 17) AFLOAD6((STL) + 1, ANXT)                                   \
    MFMA8(ACUR, BCUR)                                                          \
    if ((STL) + 3 < 18) LOADB2((STL) + 3, BCUR) }

  bh8 A0[4], A1[4];
  AFLOAD6(0, A0)
  STEPP6(0,  A0, A1, B0)
  STEPP6(1,  A1, A0, B1)
  STEPP6(2,  A0, A1, B2)
  STEPP6(3,  A1, A0, B0)
  STEPP6(4,  A0, A1, B1)
  STEPP6(5,  A1, A0, B2)
  STEPP6(6,  A0, A1, B0)
  STEPP6(7,  A1, A0, B1)
  STEPP6(8,  A0, A1, B2)
  STEPP6(9,  A1, A0, B0)
  STEPP6(10, A0, A1, B1)
  STEPP6(11, A1, A0, B2)
  STEPP6(12, A0, A1, B0)
  STEPP6(13, A1, A0, B1)
  STEPP6(14, A0, A1, B2)
  STEPP6(15, A1, A0, B0)
  STEPP6(16, A0, A1, B1)
  STEPP6(17, A1, A0, B2)
#undef LOADB2
#undef AFLOAD6
#undef MFMA8
#undef STEPP6

#pragma unroll
  for (int nf = 0; nf < 2; ++nf) {
    float s1 = 0.f, s2 = 0.f;
#pragma unroll
    for (int mf = 0; mf < 4; ++mf)
#pragma unroll
      for (int r = 0; r < 4; ++r) {
        float v = acc[mf][nf][r];
        s1 += v; s2 += v * v;
      }
    s1 += __shfl_xor(s1, 16); s2 += __shfl_xor(s2, 16);
    s1 += __shfl_xor(s1, 32); s2 += __shfl_xor(s2, 32);
    if (lane < 16) {
      int oc = n0 + nf * 16 + i16;
      atomicAdd(&statf[oc * 2], s1);
      atomicAdd(&statf[oc * 2 + 1], s2);
    }
  }
  __syncthreads();
#pragma unroll
  for (int nf = 0; nf < 2; ++nf) {
    int oc2 = (n0 + nf * 16 + i16) * 2;
#pragma unroll
    for (int mf = 0; mf < 4; ++mf)
#pragma unroll
      for (int r = 0; r < 4; ++r) {
        int px = m0 + mf * 16 + kc * 4 + r;
        *(unsigned short*)(lds + px * 128 + (oc2 ^ ((px & 7) << 4))) = f2b(acc[mf][nf][r]);
      }
  }
  __syncthreads();
  unsigned short* y2b = y2 + (long)b * NP * 64;
#pragma unroll
  for (int it = 0; it < 4; ++it) {
    int slot = (it * 256 + tid) * 16;
    int px = slot >> 7, cb = slot & 127;
    int cbs = cb ^ ((px & 7) << 4);
    f4 v = *(const f4*)(lds + px * 128 + cbs);
    *(f4*)((char*)(y2b + (long)(y * 256 + x0 + px) * 64) + cb) = v;
  }
  if (tid < 128) statp[(long)bid * 128 + tid] = statf[tid];
}

// ---------------- K7a/K7b: BN stat reduce (conv B) ----------------
__global__ __launch_bounds__(128) void k7a(const float* __restrict__ statp, float* __restrict__ p2) {
  int rblk = blockIdx.x, tid = threadIdx.x;
  float s = 0;
  for (int k = 0; k < 8; ++k) s += statp[(long)(rblk * 8 + k) * 128 + tid];
  p2[rblk * 128 + tid] = s;
}

__global__ __launch_bounds__(128) void k7b(const float* __restrict__ p2,
                                           const float* __restrict__ g2,
                                           const float* __restrict__ be2,
                                           float* __restrict__ bnB) {
  int tid = threadIdx.x;
  float s = 0;
  for (int k = 0; k < 128; ++k) s += p2[k * 128 + tid];
  __shared__ float sm[128];
  sm[tid] = s;
  __syncthreads();
  if (tid < 64) {
    int oc = tid;
    float mean = sm[oc * 2] * (1.f / 131072.f);
    float var = sm[oc * 2 + 1] * (1.f / 131072.f) - mean * mean;
    float sc = g2[oc] * rsqrtf(fmaxf(var, 0.f) + 1e-5f);
    bnB[oc * 2] = sc;
    bnB[oc * 2 + 1] = be2[oc] - mean * sc;
  }
}

// ---------------- K8: out = relu(relu(bnA(y_init)) + bnB(y2)), NCHW f32 ----------------
__global__ __launch_bounds__(256) void k8_final(const unsigned short* __restrict__ yws,
                                                const unsigned short* __restrict__ y2,
                                                const float* __restrict__ bnA,
                                                const float* __restrict__ bnB,
                                                float* __restrict__ out) {
  __shared__ float tr[64 * 77];
  int tid = threadIdx.x;
  int blk = blockIdx.x;
  int b = blk >> 10, rem = blk & 1023;
  int y = rem >> 2, xq0 = rem & 3;
  int x0 = xq0 * 64;
  int px = tid >> 2, cg = (tid & 3) * 16;
  long prow = (long)b * NP + y * 256 + x0 + px;
  const unsigned short* ysrc = yws + prow * 128 + cg;
  const unsigned short* y2src = y2 + prow * 64 + cg;
  bh8 va = *(const bh8*)ysrc;
  bh8 vb = *(const bh8*)(ysrc + 8);
  bh8 wa = *(const bh8*)y2src;
  bh8 wb = *(const bh8*)(y2src + 8);
#pragma unroll
  for (int j = 0; j < 16; ++j) {
    int c = cg + j;
    unsigned short uy = (unsigned short)(j < 8 ? va[j] : vb[j - 8]);
    unsigned short u2 = (unsigned short)(j < 8 ? wa[j] : wb[j - 8]);
    float iv = fmaxf(b2f(uy) * bnA[c * 2] + bnA[c * 2 + 1], 0.f);
    float cv = b2f(u2) * bnB[c * 2] + bnB[c * 2 + 1];
    tr[c * 77 + px] = fmaxf(iv + cv, 0.f);
  }
  __syncthreads();
  int c = tid >> 2, xq = tid & 3;
  float* orow = out + ((long)(b * 64 + c)) * NP + y * 256 + x0 + xq * 16;
  const float* trow = &tr[c * 77 + xq * 16];
#pragma unroll
  for (int j = 0; j < 16; j += 4) {
    float4 v = make_float4(trow[j], trow[j + 1], trow[j + 2], trow[j + 3]);
    *(float4*)(orow + j) = v;
  }
}

extern "C" void kernel_launch(void* const* d_in, const int* in_sizes, int n_in,
                              void* d_out, int out_size, void* d_ws, size_t ws_size,
                              hipStream_t stream) {
  if (ws_size < (size_t)WS_NEED) return;
  const float* x_i  = (const float*)d_in[0];
  const float* x_e  = (const float*)d_in[1];
  const float* y    = (const float*)d_in[2];
  const float* temp = (const float*)d_in[3];
  const float* wq   = (const float*)d_in[4];
  const float* bq   = (const float*)d_in[5];
  const float* wk   = (const float*)d_in[6];
  const float* bk   = (const float*)d_in[7];
  const float* wv   = (const float*)d_in[8];
  const float* wo   = (const float*)d_in[10];
  const float* w_init = (const float*)d_in[12];
  const float* g_init = (const float*)d_in[14];
  const float* be_init= (const float*)d_in[15];
  const float* w1   = (const float*)d_in[16];
  const float* g1   = (const float*)d_in[18];
  const float* be1  = (const float*)d_in[19];
  const float* w2   = (const float*)d_in[20];
  const float* g2   = (const float*)d_in[22];
  const float* be2  = (const float*)d_in[23];

  char* ws = (char*)d_ws;
  float* gp    = (float*)(ws + WSO_GP);
  float* Mw    = (float*)(ws + WSO_M);
  float* Sw    = (float*)(ws + WSO_S);
  float* attnW = (float*)(ws + WSO_P);
  float* Gw    = (float*)(ws + WSO_G);
  float* wtapT = (float*)(ws + WSO_WTT);
  unsigned short* wBA = (unsigned short*)(ws + WSO_WBA);
  unsigned short* wBB = (unsigned short*)(ws + WSO_WBB);
  unsigned short* xtw = (unsigned short*)(ws + WSO_XT);
  unsigned short* yws = (unsigned short*)(ws + WSO_Y);
  float* statA = (float*)(ws + WSO_STATA);
  float* p2A   = (float*)(ws + WSO_P2A);
  float* bnA   = (float*)(ws + WSO_BNA);
  unsigned short* y2w = (unsigned short*)(ws + WSO_Y2);
  float* statB = (float*)(ws + WSO_STATB);
  float* p2B   = (float*)(ws + WSO_P2B);
  float* bnB   = (float*)(ws + WSO_BNB);
  float* out   = (float*)d_out;

  hipLaunchKernelGGL(k0_prep, dim3(1024), dim3(256), 0, stream,
                     w_init, w1, w2, wtapT, wBB);
  hipLaunchKernelGGL(k1_gram, dim3(128, 2), dim3(512), 0, stream, x_i, x_e, y, gp);
  hipLaunchKernelGGL(k1_reduce, dim3(162), dim3(256), 0, stream, gp, Mw, Sw);
  hipLaunchKernelGGL(k2_attn, dim3(4, 2), dim3(256), 0, stream,
                     Mw, Sw, wq, wk, bq, bk, temp, attnW);
  hipLaunchKernelGGL(k2_g, dim3(4, 2), dim3(256), 0, stream, attnW, wo, wv, Gw);
  hipLaunchKernelGGL(k3_xt, dim3(1024, 2), dim3(256), 0, stream, x_i, x_e, xtw);
  hipLaunchKernelGGL(k3_wprep, dim3(9, 2, 8), dim3(256), 0, stream, wtapT, Gw, wBA);
  hipLaunchKernelGGL(k4_mfma, dim3(1024), dim3(256), 0, stream, xtw, wBA, yws, statA);
  hipLaunchKernelGGL(k5a, dim3(128), dim3(256), 0, stream, statA, p2A);
  hipLaunchKernelGGL(k5b, dim3(1), dim3(256), 0, stream, p2A, g_init, be_init, g1, be1, bnA);
  hipLaunchKernelGGL(k6_mfma, dim3(1024), dim3(256), 0, stream, yws, wBB, bnA, y2w, statB);
  hipLaunchKernelGGL(k7a, dim3(128), dim3(128), 0, stream, statB, p2B);
  hipLaunchKernelGGL(k7b, dim3(1), dim3(128), 0, stream, p2B, g2, be2, bnB);
  hipLaunchKernelGGL(k8_final, dim3(2048), dim3(256), 0, stream, yws, y2w, bnA, bnB, out);
}